// Round 12
// baseline (46.615 us; speedup 1.0000x reference)
//
#include <hip/hip_runtime.h>
#include <hip/hip_bf16.h>

typedef __attribute__((ext_vector_type(8))) short short8;
typedef __attribute__((ext_vector_type(4))) short short4v;
typedef __attribute__((ext_vector_type(8))) _Float16 half8;
typedef __attribute__((ext_vector_type(2))) __fp16 fp16x2;
typedef __attribute__((ext_vector_type(4))) float f32x4;

#define SPW 16384   // T*H*W spatial positions per batch
#define XST 72      // Xl row stride in shorts
#define RW  66      // Rf row stride in dwords (66%32=2 -> 2-way, free)
#define LOG2E 1.4426950408889634f

__device__ __forceinline__ float exp2_hw(float f) {
  return __builtin_amdgcn_exp2f(f);   // v_exp_f32 (base-2)
}

__device__ __forceinline__ short bf16s(float f) {
  union { __hip_bfloat16 h; short s; } u;
  u.h = __float2bfloat16(f);
  return u.s;
}

// ---------------- merged prep kernel ----------------
// a1b[(kt*64+lane)*2+s] : A-frags (16x16x32 bf16) of (-2*log2e)*E, pair contiguous
// eb3[(pr*64+lane)*4+m2]: B-frags (16x16x32 f16) of E for a kt-PAIR; slot i<4 ->
//                         k=(2pr)*16+4g+i, i>=4 -> k=(2pr+1)*16+4g+(i-4)
// norms[k]              : ||e_k||^2 * log2e
__global__ void prep_all(const float* __restrict__ emb, short8* __restrict__ a1b,
                         half8* __restrict__ eb3, float* __restrict__ norms) {
  const int f = blockIdx.x * 256 + threadIdx.x;
  if (f < 4096) {
    const int s = f & 1;
    const int lane = (f >> 1) & 63;
    const int kt = f >> 7;
    const int row = kt * 16 + (lane & 15);
    const int col0 = s * 32 + (lane >> 4) * 8;
    short8 v;
    #pragma unroll
    for (int i = 0; i < 8; ++i)
      v[i] = bf16s(-2.0f * LOG2E * emb[row * 64 + col0 + i]);
    a1b[f] = v;
  } else if (f < 8192) {
    const int e = f - 4096;
    const int m2 = e & 3;
    const int lane = (e >> 2) & 63;
    const int pr = e >> 8;               // kt-pair 0..15
    const int g = lane >> 4;
    const int d = m2 * 16 + (lane & 15);
    half8 v;
    #pragma unroll
    for (int i = 0; i < 8; ++i) {
      const int k = (i < 4) ? (pr * 32 + 4 * g + i) : (pr * 32 + 16 + 4 * g + (i - 4));
      v[i] = (_Float16)emb[k * 64 + d];
    }
    eb3[e] = v;
  } else if (f < 8704) {
    const int k = f - 8192;
    float acc = 0.f;
    #pragma unroll
    for (int d = 0; d < 64; ++d) { float e = emb[k * 64 + d]; acc += e * e; }
    norms[k] = acc * LOG2E;
  }
}

// per-iteration fragment set (register double-buffered)
struct Frags {
  short8 aA0, aA1, aB0, aB1;
  half8 e0, e1, e2, e3;
  float4 nvA, nvB;
};

__device__ __forceinline__ void ldfrag(Frags& f, const short8* __restrict__ a1b,
                                       const half8* __restrict__ eb3,
                                       const float* __restrict__ norms,
                                       int pr, int lane, int g) {
  const int ktA = pr * 2;
  f.nvA = *reinterpret_cast<const float4*>(&norms[ktA * 16 + g * 4]);
  f.nvB = *reinterpret_cast<const float4*>(&norms[ktA * 16 + 16 + g * 4]);
  const short8* ap = &a1b[(ktA * 64 + lane) * 2];
  f.aA0 = ap[0];
  f.aA1 = ap[1];
  f.aB0 = ap[128];             // ktB = ktA+1 -> +64*2 short8
  f.aB1 = ap[129];
  const half8* ep = &eb3[(pr * 64 + lane) * 4];   // 64B contiguous
  f.e0 = ep[0];
  f.e1 = ep[1];
  f.e2 = ep[2];
  f.e3 = ep[3];
}

__device__ __forceinline__ half8 make_pa(float p0, float p1, float p2, float p3,
                                         float p4, float p5, float p6, float p7) {
  const unsigned a = __builtin_bit_cast(unsigned, __builtin_amdgcn_cvt_pkrtz(p0, p1));
  const unsigned b = __builtin_bit_cast(unsigned, __builtin_amdgcn_cvt_pkrtz(p2, p3));
  const unsigned c = __builtin_bit_cast(unsigned, __builtin_amdgcn_cvt_pkrtz(p4, p5));
  const unsigned d = __builtin_bit_cast(unsigned, __builtin_amdgcn_cvt_pkrtz(p6, p7));
  const uint4 u = {a, b, c, d};
  return __builtin_bit_cast(half8, u);
}

__device__ __forceinline__ void compute_unit(const Frags& f, const short8 bx[2][2],
                                             f32x4 pacc[2][4], f32x4 dacc[2],
                                             const half8 ones) {
  #pragma unroll
  for (int j = 0; j < 2; ++j) {
    f32x4 zA = {f.nvA.x, f.nvA.y, f.nvA.z, f.nvA.w};   // norm term as C-init
    zA = __builtin_amdgcn_mfma_f32_16x16x32_bf16(f.aA0, bx[j][0], zA, 0, 0, 0);
    zA = __builtin_amdgcn_mfma_f32_16x16x32_bf16(f.aA1, bx[j][1], zA, 0, 0, 0);
    f32x4 zB = {f.nvB.x, f.nvB.y, f.nvB.z, f.nvB.w};
    zB = __builtin_amdgcn_mfma_f32_16x16x32_bf16(f.aB0, bx[j][0], zB, 0, 0, 0);
    zB = __builtin_amdgcn_mfma_f32_16x16x32_bf16(f.aB1, bx[j][1], zB, 0, 0, 0);
    const float p0 = exp2_hw(zA[0]);
    const float p1 = exp2_hw(zA[1]);
    const float p2 = exp2_hw(zA[2]);
    const float p3 = exp2_hw(zA[3]);
    const float p4 = exp2_hw(zB[0]);
    const float p5 = exp2_hw(zB[1]);
    const float p6 = exp2_hw(zB[2]);
    const float p7 = exp2_hw(zB[3]);
    const half8 pa = make_pa(p0, p1, p2, p3, p4, p5, p6, p7);
    pacc[j][0] = __builtin_amdgcn_mfma_f32_16x16x32_f16(pa, f.e0, pacc[j][0], 0, 0, 0);
    pacc[j][1] = __builtin_amdgcn_mfma_f32_16x16x32_f16(pa, f.e1, pacc[j][1], 0, 0, 0);
    pacc[j][2] = __builtin_amdgcn_mfma_f32_16x16x32_f16(pa, f.e2, pacc[j][2], 0, 0, 0);
    pacc[j][3] = __builtin_amdgcn_mfma_f32_16x16x32_f16(pa, f.e3, pacc[j][3], 0, 0, 0);
    // den: ones-MFMA -> dacc[j][r] = den[n=j*16+4g+r] (replicated over l15)
    dacc[j] = __builtin_amdgcn_mfma_f32_16x16x32_f16(pa, ones, dacc[j], 0, 0, 0);
  }
}

// ---------------- main kernel ----------------
// 4-wave blocks, 32 shared n-columns; wave kg owns k [kg*128,+128) as 4 kt-pairs.
// logits(base2) = log2e*||e||^2 - 2log2e*(x.e); norm rides the mfma1 C-init; exp2
// needs no max (|logit| tiny; softmax shift-invariance). mfma1 C-layout
// (col=l15,row=4g+r) == A-layout slots of mfma_f32_16x16x32_f16 -> P feeds mfma2
// in-register. Frag stream double-buffered in registers; ~125 regs -> (256,3)
// gives 3 waves/SIMD (vs R11's 2) for stall overlap at the env's ~1 GHz clock.
__global__ __launch_bounds__(256, 3) void vq_main(
    const float* __restrict__ x, const short8* __restrict__ a1b,
    const half8* __restrict__ eb3, const float* __restrict__ norms,
    float* __restrict__ out) {
  __shared__ __align__(16) char lds_raw[34432];
  short* Xl   = reinterpret_cast<short*>(lds_raw);            // [32][72] bf16 (staging)
  float* Rf   = reinterpret_cast<float*>(lds_raw);            // [128][66] f32 (epilogue)
  float* denl = reinterpret_cast<float*>(lds_raw + 33792);    // [4][32]

  const int t = threadIdx.x;
  const int lane = t & 63;
  const int kg = t >> 6;       // k group: kt-pairs [kg*4, kg*4+4)
  const int l15 = lane & 15;
  const int g = lane >> 4;

  const int tile = blockIdx.x * 32;
  const int b = tile >> 14;
  const int off = tile & 16383;
  const float* xb = x + (size_t)b * (64 * SPW) + off;
  float* ob = out + (size_t)b * (64 * SPW) + off;

  // stage X tile: threads 0..127, each a 4d x 4n fp32 micro-tile -> Xl[n][d] bf16
  if (t < 128) {
    const int n0 = 4 * (t & 7);
    const int d0 = 4 * (t >> 3);
    const float4 r0 = *reinterpret_cast<const float4*>(xb + (size_t)(d0 + 0) * SPW + n0);
    const float4 r1 = *reinterpret_cast<const float4*>(xb + (size_t)(d0 + 1) * SPW + n0);
    const float4 r2 = *reinterpret_cast<const float4*>(xb + (size_t)(d0 + 2) * SPW + n0);
    const float4 r3 = *reinterpret_cast<const float4*>(xb + (size_t)(d0 + 3) * SPW + n0);
    const short4v c0 = {bf16s(r0.x), bf16s(r1.x), bf16s(r2.x), bf16s(r3.x)};
    const short4v c1 = {bf16s(r0.y), bf16s(r1.y), bf16s(r2.y), bf16s(r3.y)};
    const short4v c2 = {bf16s(r0.z), bf16s(r1.z), bf16s(r2.z), bf16s(r3.z)};
    const short4v c3 = {bf16s(r0.w), bf16s(r1.w), bf16s(r2.w), bf16s(r3.w)};
    *reinterpret_cast<short4v*>(&Xl[(n0 + 0) * XST + d0]) = c0;
    *reinterpret_cast<short4v*>(&Xl[(n0 + 1) * XST + d0]) = c1;
    *reinterpret_cast<short4v*>(&Xl[(n0 + 2) * XST + d0]) = c2;
    *reinterpret_cast<short4v*>(&Xl[(n0 + 3) * XST + d0]) = c3;
  }
  __syncthreads();

  // bx: matmul1 B-frags for the 32 shared columns (16 VGPR)
  short8 bx[2][2];
  #pragma unroll
  for (int j = 0; j < 2; ++j) {
    const int base = (j * 16 + l15) * XST + g * 8;
    bx[j][0] = *reinterpret_cast<const short8*>(&Xl[base]);
    bx[j][1] = *reinterpret_cast<const short8*>(&Xl[base + 32]);
  }
  __syncthreads();   // all Xl reads done before Rf (aliased) is written later

  f32x4 pacc[2][4];
  #pragma unroll
  for (int j = 0; j < 2; ++j)
    #pragma unroll
    for (int m2 = 0; m2 < 4; ++m2) pacc[j][m2] = f32x4{0.f, 0.f, 0.f, 0.f};
  f32x4 dacc[2] = {f32x4{0.f, 0.f, 0.f, 0.f}, f32x4{0.f, 0.f, 0.f, 0.f}};
  const half8 ones = {(_Float16)1.f, (_Float16)1.f, (_Float16)1.f, (_Float16)1.f,
                      (_Float16)1.f, (_Float16)1.f, (_Float16)1.f, (_Float16)1.f};

  // main loop: 4 kt-pairs, register double-buffered (p+1 loads fly during p)
  const int prb = kg * 4;
  Frags fA, fB;
  ldfrag(fA, a1b, eb3, norms, prb + 0, lane, g);
  ldfrag(fB, a1b, eb3, norms, prb + 1, lane, g);
  compute_unit(fA, bx, pacc, dacc, ones);
  ldfrag(fA, a1b, eb3, norms, prb + 2, lane, g);
  compute_unit(fB, bx, pacc, dacc, ones);
  ldfrag(fB, a1b, eb3, norms, prb + 3, lane, g);
  compute_unit(fA, bx, pacc, dacc, ones);
  compute_unit(fB, bx, pacc, dacc, ones);

  // den partials -> denl[kg][n]; dacc[j][r] = den[n=j*16+4g+r], uniform over l15
  if (l15 == 0) {
    #pragma unroll
    for (int j = 0; j < 2; ++j)
      #pragma unroll
      for (int r = 0; r < 4; ++r)
        denl[kg * 32 + j * 16 + 4 * g + r] = dacc[j][r];
  }

  // Num^T partial -> Rf[kg*32 + n][d]
  #pragma unroll
  for (int j = 0; j < 2; ++j)
    #pragma unroll
    for (int m2 = 0; m2 < 4; ++m2)
      #pragma unroll
      for (int r = 0; r < 4; ++r)
        Rf[(kg * 32 + j * 16 + 4 * g + r) * RW + m2 * 16 + l15] = pacc[j][m2][r];
  __syncthreads();

  // epilogue: 4-way k-reduce + divide + store; 8 threads x float4 = 128B per d-row
  const int n4 = 4 * (t & 7);
  const int dbase = t >> 3;    // 0..31
  f32x4 rd;
  #pragma unroll
  for (int i = 0; i < 4; ++i) {
    const int n = n4 + i;
    rd[i] = 1.0f / ((denl[n] + denl[32 + n]) + (denl[64 + n] + denl[96 + n]));
  }
  #pragma unroll
  for (int it = 0; it < 2; ++it) {
    const int d = it * 32 + dbase;
    float4 o;
    #pragma unroll
    for (int i = 0; i < 4; ++i) {
      const int n = n4 + i;
      const float s = (Rf[n * RW + d] + Rf[(32 + n) * RW + d])
                    + (Rf[(64 + n) * RW + d] + Rf[(96 + n) * RW + d]);
      reinterpret_cast<float*>(&o)[i] = s * rd[i];
    }
    *reinterpret_cast<float4*>(&ob[(size_t)d * SPW + n4]) = o;
  }
}

extern "C" void kernel_launch(void* const* d_in, const int* in_sizes, int n_in,
                              void* d_out, int out_size, void* d_ws, size_t ws_size,
                              hipStream_t stream) {
  (void)in_sizes; (void)n_in; (void)out_size; (void)ws_size;
  const float* x   = (const float*)d_in[0];   // (8, 64, 16, 32, 32) fp32
  const float* emb = (const float*)d_in[1];   // (512, 64) fp32
  float* out = (float*)d_out;

  char* ws = (char*)d_ws;
  short8* a1b  = (short8*)ws;                 // 65536 B
  half8*  eb3  = (half8*)(ws + 65536);        // 65536 B
  float*  norms = (float*)(ws + 131072);      // 2048 B

  prep_all<<<34, 256, 0, stream>>>(emb, a1b, eb3, norms);
  vq_main<<<4096, 256, 0, stream>>>(x, a1b, eb3, norms, out);
}